// Round 9
// baseline (965.710 us; speedup 1.0000x reference)
//
#include <hip/hip_runtime.h>

typedef __bf16 bf16;
typedef __bf16 bf16x4 __attribute__((ext_vector_type(4)));
typedef __bf16 bf16x8 __attribute__((ext_vector_type(8)));
typedef float f32x4 __attribute__((ext_vector_type(4)));
typedef float f32x16 __attribute__((ext_vector_type(16)));
typedef int i32x2 __attribute__((ext_vector_type(2)));
typedef unsigned int u32;

#define DIMC 384
#define NHEADS 12
#define NTOK 49
#define NWINB 4096
#define MROWS (NWINB*NTOK)   // 200704

#define MFMA32(A,B,C) __builtin_amdgcn_mfma_f32_32x32x16_bf16(A,B,C,0,0,0)

// async global->LDS, 16B per lane; LDS dest is wave-uniform base + lane*16
#define GLOAD16(gsrc, lbase) \
  __builtin_amdgcn_global_load_lds( \
      (const __attribute__((address_space(1))) u32*)(gsrc), \
      (__attribute__((address_space(3))) u32*)(lbase), 16, 0, 0)

// ---------------- convert f32 -> bf16 (vectorized) ----------------
__global__ __launch_bounds__(256) void k_convert(const float4* __restrict__ in,
                                                 bf16x4* __restrict__ out, int n4) {
  int stride = gridDim.x * blockDim.x;
  for (int i = blockIdx.x * blockDim.x + threadIdx.x; i < n4; i += stride) {
    float4 v = in[i];
    bf16x4 o;
    o[0] = (bf16)v.x; o[1] = (bf16)v.y; o[2] = (bf16)v.z; o[3] = (bf16)v.w;
    out[i] = o;
  }
}

// ---------------- zero only vT pad keys [48,64) per (p,d): 32B each ----------------
__global__ __launch_bounds__(256) void k_padzero(bf16* __restrict__ vT) {
  int i = blockIdx.x * 256 + threadIdx.x;       // i = p*32 + d, total 49152*32
  float4 z = {0.f, 0.f, 0.f, 0.f};
  float4* p = reinterpret_cast<float4*>(vT + (size_t)i * 64 + 48);
  p[0] = z; p[1] = z;
}

// ---------------- combined transposed bias+mask table ----------------
// bmT[(h*64+w)][key*49+q] = table[rel[q*49+key]*12+h] + mask[(w*49+q)*49+key]
__global__ __launch_bounds__(256) void k_bm(const float* __restrict__ table,
                                            const int* __restrict__ rel,
                                            const float* __restrict__ mask,
                                            float* __restrict__ outp) {
  int i = blockIdx.x * 256 + threadIdx.x;
  if (i < NHEADS * 64 * NTOK * NTOK) {
    int hw = i / 2401, r2 = i - hw * 2401;
    int h = hw >> 6, w = hw & 63;
    int key = r2 / NTOK, q = r2 - key * NTOK;
    outp[i] = table[rel[q * NTOK + key] * NHEADS + h] + mask[(w * NTOK + q) * NTOK + key];
  }
}

// ---------------- GEMM: C = A(M,K) * Bw(N,K)^T, bf16 in, f32 acc ----------------
// BM=64 x BN=128 x BK=64, double-buffered, counted vmcnt(6), XOR-swizzled LDS
// via pre-swizzled global source, XCD-chunk remap (contiguous M-panels/XCD).
// MODE 0: QKV (N=1152) -> q,k packed (p,49,32) direct; v transposed vT
// (p,32,64) via LDS-transpose epilogue (coalesced token-runs, no lane scatter).
// MODE 1: proj (N=384) -> f32 out + bias.
template <int MODE>
__global__ __launch_bounds__(256) void k_gemm(const bf16* __restrict__ A,
                                              const bf16* __restrict__ Bw,
                                              const float* __restrict__ bias,
                                              bf16* __restrict__ oQ, bf16* __restrict__ oK,
                                              bf16* __restrict__ oV, float* __restrict__ oP) {
  __shared__ __align__(16) bf16 lA[2][64 * 64];
  __shared__ __align__(16) bf16 lB[2][128 * 64];
  const int t = threadIdx.x;
  const int l = t & 63;
  const int wv = t >> 6;
  const int wr = wv >> 1, wc = wv & 1;   // 2x2 waves: each 32(M) x 64(N)

  const u32 NXB = MODE == 0 ? 9 : 3;                 // N-blocks (128-wide)
  const u32 nwg = NXB * (MROWS / 64);
  u32 lin = blockIdx.y * gridDim.x + blockIdx.x;
  u32 logical = (lin & 7) * (nwg >> 3) + (lin >> 3);
  const int n0 = (int)(logical % NXB) * 128;
  const int m0 = (int)(logical / NXB) * 64;

  const int lr = l & 15, lg = l >> 4;

  const int srowA = wv * 16 + (l >> 3);
  const int srowB = wv * 32 + (l >> 3);
  const int scolb = (l & 7) * 16;

  f32x4 acc[2][4] = {};

#define STAGE(BUF, K0)                                                            \
  {                                                                               \
    _Pragma("unroll") for (int i = 0; i < 2; ++i) {                               \
      int row = srowA + i * 8;                                                    \
      int sc = (scolb ^ ((row & 7) << 4)) >> 1;                                   \
      GLOAD16(&A[(size_t)(m0 + row) * DIMC + (K0) + sc],                          \
              &lA[BUF][wv * 1024 + i * 512]);                                     \
    }                                                                             \
    _Pragma("unroll") for (int i = 0; i < 4; ++i) {                               \
      int row = srowB + i * 8;                                                    \
      int sc = (scolb ^ ((row & 7) << 4)) >> 1;                                   \
      GLOAD16(&Bw[(size_t)(n0 + row) * DIMC + (K0) + sc],                         \
              &lB[BUF][wv * 2048 + i * 512]);                                     \
    }                                                                             \
  }

  STAGE(0, 0);

#pragma unroll
  for (int tt = 0; tt < 6; ++tt) {
    const int cur = tt & 1;
    if (tt > 0) __builtin_amdgcn_s_barrier();
    if (tt < 5) {
      STAGE(cur ^ 1, (tt + 1) * 64);
      asm volatile("s_waitcnt vmcnt(6)" ::: "memory");
    } else {
      asm volatile("s_waitcnt vmcnt(0)" ::: "memory");
    }
    __builtin_amdgcn_s_barrier();

#pragma unroll
    for (int kk = 0; kk < 64; kk += 32) {
      bf16x8 af[2], bfv[4];
#pragma unroll
      for (int f = 0; f < 2; ++f) {
        int row = wr * 32 + f * 16 + lr;
        int cb = (kk + lg * 8) * 2;
        af[f] = *reinterpret_cast<const bf16x8*>(
            &lA[cur][row * 64 + ((cb ^ ((row & 7) << 4)) >> 1)]);
      }
#pragma unroll
      for (int f = 0; f < 4; ++f) {
        int row = wc * 64 + f * 16 + lr;
        int cb = (kk + lg * 8) * 2;
        bfv[f] = *reinterpret_cast<const bf16x8*>(
            &lB[cur][row * 64 + ((cb ^ ((row & 7) << 4)) >> 1)]);
      }
#pragma unroll
      for (int fm = 0; fm < 2; ++fm)
#pragma unroll
        for (int fn = 0; fn < 4; ++fn)
          acc[fm][fn] = __builtin_amdgcn_mfma_f32_16x16x32_bf16(af[fm], bfv[fn], acc[fm][fn], 0, 0, 0);
    }
  }
#undef STAGE

  // epilogue: C/D frag mapping col = lane&15, row = (lane>>4)*4 + r  [m89-verified]
  const int cbase = n0 + wc * 64;
  if constexpr (MODE == 0) {
    if (n0 >= 768) {
      // ---- V blocks: LDS transpose -> coalesced vT writes ----
      __shared__ __align__(4) bf16 et[64 * 130];   // stride 130: conflict-free both phases
#pragma unroll
      for (int fn = 0; fn < 4; ++fn) {
        const float bc = bias[cbase + fn * 16 + lr];
        const int col = wc * 64 + fn * 16 + lr;
#pragma unroll
        for (int fm = 0; fm < 2; ++fm) {
#pragma unroll
          for (int r = 0; r < 4; ++r) {
            const int row = wr * 32 + fm * 16 + lg * 4 + r;
            et[row * 130 + col] = (bf16)(acc[fm][fn][r] + bc);
          }
        }
      }
      __syncthreads();
      // lane = token (row), iterate cols: writes form contiguous token-runs in vT
      const int vbase = n0 - 768;
      const int m = m0 + l;
      const int bi = m / 49, n = m - bi * 49;
#pragma unroll
      for (int cc = 0; cc < 32; ++cc) {
        const int col = wv * 32 + cc;
        const bf16 val = et[l * 130 + col];
        const int vcol = vbase + col;
        const int h = vcol >> 5, d = vcol & 31;
        oV[((size_t)bi * 12 + h) * 2048 + d * 64 + n] = val;
      }
    } else {
      // ---- Q/K blocks: packed (p,49,32) direct stores ----
      const int which = cbase / 384;            // 0 (q) or 1 (k), wave-uniform
      const int colh = cbase - which * 384;
      bf16* dst = which == 0 ? oQ : oK;
#pragma unroll
      for (int fn = 0; fn < 4; ++fn) {
        const int cc = colh + fn * 16 + lr;
        const int h = cc >> 5, d = cc & 31;
        const float bc = bias[cbase + fn * 16 + lr];
#pragma unroll
        for (int fm = 0; fm < 2; ++fm) {
#pragma unroll
          for (int r = 0; r < 4; ++r) {
            const int m = m0 + wr * 32 + fm * 16 + lg * 4 + r;
            const int bi = m / 49, n = m - bi * 49;
            dst[(((size_t)bi * 12 + h) * 49 + n) * 32 + d] = (bf16)(acc[fm][fn][r] + bc);
          }
        }
      }
    }
  } else {
#pragma unroll
    for (int fn = 0; fn < 4; ++fn) {
      const int c = cbase + fn * 16 + lr;
      const float bc = bias[c];
#pragma unroll
      for (int fm = 0; fm < 2; ++fm) {
#pragma unroll
        for (int r = 0; r < 4; ++r) {
          const int m = m0 + wr * 32 + fm * 16 + lg * 4 + r;
          oP[(size_t)m * 384 + c] = acc[fm][fn][r] + bc;
        }
      }
    }
  }
}

// ---------------- fused window attention: one wave per (b,h), 32x32 MFMA ----------------
// Zero LDS, zero barriers. Q/K packed (p,49,32); V pre-transposed (p,32,64) so
// PV B-fragments are direct 16B global loads. bias+mask pre-combined in bmT.
__global__ __launch_bounds__(256, 4) void k_attn(const bf16* __restrict__ Q,
                                                 const bf16* __restrict__ K,
                                                 const bf16* __restrict__ VT,
                                                 const float* __restrict__ bmT,
                                                 bf16* __restrict__ H) {
  const int t = threadIdx.x, l = t & 63, wv = t >> 6;
  const int p = blockIdx.x * 4 + wv;   // b*12 + h
  const int b = p / 12, h = p - b * 12;
  const int w = b & 63;
  const size_t base = (size_t)p * (49 * 32);
  const int c = l & 31, b5 = l >> 5;

  // V fragments straight from transposed global layout:
  // lane (c,b5) holds V[key = kk*16 + b5*8 + j][d = c] = VT[p][c][kk*16+b5*8+j]
  bf16x8 vf[4];
#pragma unroll
  for (int kk = 0; kk < 4; ++kk)
    vf[kk] = *reinterpret_cast<const bf16x8*>(&VT[(size_t)p * 2048 + c * 64 + kk * 16 + b5 * 8]);

  bf16x8 kf[2][2], qf[2][2];
#pragma unroll
  for (int f = 0; f < 2; ++f) {
    int row = f * 32 + c; if (row > 48) row = 48;
#pragma unroll
    for (int kd = 0; kd < 2; ++kd) {
      kf[f][kd] = *reinterpret_cast<const bf16x8*>(&K[base + row * 32 + kd * 16 + b5 * 8]);
      qf[f][kd] = *reinterpret_cast<const bf16x8*>(&Q[base + row * 32 + kd * 16 + b5 * 8]);
    }
  }

  const float scale = 0.17677669529663689f;   // 32^-0.5
  const float* bm = bmT + ((size_t)h * 64 + w) * 2401;

#pragma unroll
  for (int fn = 0; fn < 2; ++fn) {
    // swapped QK^T: S[key][q], C layout col=lane&31=q, row=(r&3)+8*(r>>2)+4*b5=key
    f32x16 s0 = {}, s1 = {};
    s0 = MFMA32(kf[0][0], qf[fn][0], s0);
    s0 = MFMA32(kf[0][1], qf[fn][1], s0);
    s1 = MFMA32(kf[1][0], qf[fn][0], s1);
    s1 = MFMA32(kf[1][1], qf[fn][1], s1);

    int q = fn * 32 + c;
    int qc = q > 48 ? 48 : q;

    float vals[32];
    float vmax = -1e30f;
#pragma unroll
    for (int fm = 0; fm < 2; ++fm) {
#pragma unroll
      for (int r = 0; r < 16; ++r) {
        int key = fm * 32 + (r & 3) + 8 * (r >> 2) + 4 * b5;
        float sv = fm ? s1[r] : s0[r];
        float v;
        if (key < 49) {
          v = fmaf(sv, scale, bm[key * 49 + qc]);
        } else {
          v = -1e30f;
        }
        vals[fm * 16 + r] = v;
        vmax = fmaxf(vmax, v);
      }
    }
    vmax = fmaxf(vmax, __shfl_xor(vmax, 32));
    float sum = 0.f;
#pragma unroll
    for (int i = 0; i < 32; ++i) {
      float e = __expf(vals[i] - vmax);
      vals[i] = e;
      sum += e;
    }
    sum += __shfl_xor(sum, 32);
    float inv = 1.f / sum;

    // PV: build P A-frags in-register (cvt pack + permlane32_swap), MFMA with vf
    f32x16 o = {};
#pragma unroll
    for (int kk = 0; kk < 4; ++kk) {
      int ib = (kk >> 1) * 16 + 8 * (kk & 1);
      union { bf16 hh[2]; u32 u; } cv;
      u32 A0, A1, B0, B1;
      cv.hh[0] = (bf16)(vals[ib + 0] * inv); cv.hh[1] = (bf16)(vals[ib + 1] * inv); A0 = cv.u;
      cv.hh[0] = (bf16)(vals[ib + 2] * inv); cv.hh[1] = (bf16)(vals[ib + 3] * inv); A1 = cv.u;
      cv.hh[0] = (bf16)(vals[ib + 4] * inv); cv.hh[1] = (bf16)(vals[ib + 5] * inv); B0 = cv.u;
      cv.hh[0] = (bf16)(vals[ib + 6] * inv); cv.hh[1] = (bf16)(vals[ib + 7] * inv); B1 = cv.u;
      i32x2 sw0 = __builtin_amdgcn_permlane32_swap((int)A0, (int)B0, false, false);
      i32x2 sw1 = __builtin_amdgcn_permlane32_swap((int)A1, (int)B1, false, false);
      union { u32 d[4]; bf16x8 v8; } pa;
      pa.d[0] = (u32)sw0[0]; pa.d[1] = (u32)sw1[0];
      pa.d[2] = (u32)sw0[1]; pa.d[3] = (u32)sw1[1];
      o = MFMA32(pa.v8, vf[kk], o);
    }

#pragma unroll
    for (int r = 0; r < 16; ++r) {
      int qrow = fn * 32 + (r & 3) + 8 * (r >> 2) + 4 * b5;
      if (qrow < 49)
        H[((size_t)b * 49 + qrow) * 384 + h * 32 + c] = (bf16)o[r];
    }
  }
}

extern "C" void kernel_launch(void* const* d_in, const int* in_sizes, int n_in,
                              void* d_out, int out_size, void* d_ws, size_t ws_size,
                              hipStream_t stream) {
  const float* x     = (const float*)d_in[0];
  const float* mask  = (const float*)d_in[1];
  const float* qkvw  = (const float*)d_in[2];
  const float* qkvb  = (const float*)d_in[3];
  const float* btab  = (const float*)d_in[4];
  const float* projw = (const float*)d_in[5];
  const float* projb = (const float*)d_in[6];
  const int*   rel   = (const int*)d_in[7];
  float* out = (float*)d_out;

  const size_t NB  = 154140672;   // one [200704][384] bf16 buffer (bytes)
  const size_t VTB = 201326592;   // vT: 49152 heads * 32 d * 64 keys * 2B
  const size_t BMB = 7375872;     // bmT: 12*64*2401 f32
  char* ws = (char*)d_ws;
  // ws layout: xb/h | vT | bmT | wqkv | wproj   (~364 MB)
  bf16*  xb    = (bf16*)ws;
  bf16*  vT    = (bf16*)(ws + NB);
  float* bmT   = (float*)(ws + NB + VTB);
  bf16*  wqkv  = (bf16*)(ws + NB + VTB + BMB);
  bf16*  wproj = (bf16*)(ws + NB + VTB + BMB + 884736);
  // q,k packed (p,49,32) live in d_out scratch (2*154,140,672 B exactly)
  bf16* qb = (bf16*)d_out;
  bf16* kb = qb + NB / 2;

  k_convert<<<2048, 256, 0, stream>>>((const float4*)x, (bf16x4*)xb, (int)(NB / 8));
  k_convert<<<432, 256, 0, stream>>>((const float4*)qkvw, (bf16x4*)wqkv, 3 * DIMC * DIMC / 4);
  k_convert<<<144, 256, 0, stream>>>((const float4*)projw, (bf16x4*)wproj, DIMC * DIMC / 4);
  k_bm<<<(NHEADS * 64 * NTOK * NTOK + 255) / 256, 256, 0, stream>>>(btab, rel, mask, bmT);
  k_padzero<<<6144, 256, 0, stream>>>(vT);   // pad keys [48,64) finite-zero

  k_gemm<0><<<dim3(9, MROWS / 64), 256, 0, stream>>>(xb, wqkv, qkvb, qb, kb, vT, nullptr);
  k_attn<<<(NWINB * NHEADS) / 4, 256, 0, stream>>>(qb, kb, vT, bmT, xb);
  k_gemm<1><<<dim3(3, MROWS / 64), 256, 0, stream>>>(xb, wproj, projb, nullptr, nullptr, nullptr, out);
}

// Round 13
// 795.351 us; speedup vs baseline: 1.2142x; 1.2142x over previous
//
#include <hip/hip_runtime.h>

typedef __bf16 bf16;
typedef __bf16 bf16x4 __attribute__((ext_vector_type(4)));
typedef __bf16 bf16x8 __attribute__((ext_vector_type(8)));
typedef float f32x4 __attribute__((ext_vector_type(4)));
typedef float f32x16 __attribute__((ext_vector_type(16)));
typedef int i32x2 __attribute__((ext_vector_type(2)));
typedef unsigned int u32;

#define DIMC 384
#define NHEADS 12
#define NTOK 49
#define NWINB 4096
#define MROWS (NWINB*NTOK)   // 200704

#define MFMA32(A,B,C) __builtin_amdgcn_mfma_f32_32x32x16_bf16(A,B,C,0,0,0)

// async global->LDS, 16B per lane; LDS dest is wave-uniform base + lane*16.
// NOTE: static __shared__ staging only; NEVER reuse this staging region for
// ds_write traffic later in the kernel (r10-r12: et aliased on staging LDS
// -> nondeterministic corruption; r6-r9 separate/non-aliased all green).
#define GLOAD16(gsrc, lbase) \
  __builtin_amdgcn_global_load_lds( \
      (const __attribute__((address_space(1))) u32*)(gsrc), \
      (__attribute__((address_space(3))) u32*)(lbase), 16, 0, 0)

// ---------------- convert f32 -> bf16 (vectorized) ----------------
__global__ __launch_bounds__(256) void k_convert(const float4* __restrict__ in,
                                                 bf16x4* __restrict__ out, int n4) {
  int stride = gridDim.x * blockDim.x;
  for (int i = blockIdx.x * blockDim.x + threadIdx.x; i < n4; i += stride) {
    float4 v = in[i];
    bf16x4 o;
    o[0] = (bf16)v.x; o[1] = (bf16)v.y; o[2] = (bf16)v.z; o[3] = (bf16)v.w;
    out[i] = o;
  }
}

// ---------------- combined transposed bias+mask table (r8/r9-proven) ----------------
// bmT[(h*64+w)][key*49+q] = table[rel[q*49+key]*12+h] + mask[(w*49+q)*49+key]
__global__ __launch_bounds__(256) void k_bm(const float* __restrict__ table,
                                            const int* __restrict__ rel,
                                            const float* __restrict__ mask,
                                            float* __restrict__ outp) {
  int i = blockIdx.x * 256 + threadIdx.x;
  if (i < NHEADS * 64 * NTOK * NTOK) {
    int hw = i / 2401, r2 = i - hw * 2401;
    int h = hw >> 6, w = hw & 63;
    int key = r2 / NTOK, q = r2 - key * NTOK;
    outp[i] = table[rel[q * NTOK + key] * NHEADS + h] + mask[(w * NTOK + q) * NTOK + key];
  }
}

// ---------------- GEMM: C = A(M,K) * Bw(N,K)^T, bf16 in, f32 acc ----------------
// (round-5 green, byte-identical) BM=128 x BN=128 x BK=64, double-buffered,
// counted vmcnt(8), raw s_barriers, XOR-swizzled static LDS via pre-swizzled
// global source, XCD-chunk remap (contiguous M-panels per XCD).
// MODE 0: QKV (N=1152), scatter q/k/v packed (p,49,32).  MODE 1: proj -> f32+bias.
template <int MODE>
__global__ __launch_bounds__(256) void k_gemm(const bf16* __restrict__ A,
                                              const bf16* __restrict__ Bw,
                                              const float* __restrict__ bias,
                                              bf16* __restrict__ oQ, bf16* __restrict__ oK,
                                              bf16* __restrict__ oV, float* __restrict__ oP) {
  __shared__ __align__(16) bf16 lA[2][128 * 64];
  __shared__ __align__(16) bf16 lB[2][128 * 64];
  const int t = threadIdx.x;
  const int l = t & 63;
  const int wv = t >> 6;
  const int wr = wv >> 1, wc = wv & 1;   // 2x2 waves, 64x64 each

  // ---- bijective XCD-chunk remap (nwg % 8 == 0 for both modes) ----
  const u32 NXB = MODE == 0 ? 9 : 3;                 // N-blocks
  const u32 nwg = NXB * (MROWS / 128);
  u32 lin = blockIdx.y * gridDim.x + blockIdx.x;     // dispatch-linear (x fastest)
  u32 logical = (lin & 7) * (nwg >> 3) + (lin >> 3); // XCD gets contiguous chunk
  const int n0 = (int)(logical % NXB) * 128;
  const int m0 = (int)(logical / NXB) * 128;

  const int lr = l & 15, lg = l >> 4;

  // staging geometry: lane's linear tile byte offset = wv*4096 + i*1024 + l*16
  const int srow = wv * 32 + (l >> 3);           // + i*8 per issue
  const int scolb = (l & 7) * 16;                // byte col within 128B row

  f32x4 acc[4][4] = {};

  // per-lane pre-swizzled source column (elements) for each of the 4 issues
  int scolA[4];
#pragma unroll
  for (int i = 0; i < 4; ++i) {
    int row = srow + i * 8;
    scolA[i] = (scolb ^ ((row & 7) << 4)) >> 1;
  }

#define STAGE(BUF, K0)                                                            \
  {                                                                               \
    _Pragma("unroll") for (int i = 0; i < 4; ++i) {                               \
      int row = srow + i * 8;                                                     \
      GLOAD16(&A[(size_t)(m0 + row) * DIMC + (K0) + scolA[i]],                    \
              &lA[BUF][wv * 2048 + i * 512]);                                     \
      GLOAD16(&Bw[(size_t)(n0 + row) * DIMC + (K0) + scolA[i]],                   \
              &lB[BUF][wv * 2048 + i * 512]);                                     \
    }                                                                             \
  }

  STAGE(0, 0);                      // prologue: tile 0 in flight

#pragma unroll
  for (int tt = 0; tt < 6; ++tt) {  // K = 384 = 6 x 64, fully unrolled
    const int cur = tt & 1;
    if (tt > 0) __builtin_amdgcn_s_barrier();      // compute(tt-1) done -> buf reuse safe
    if (tt < 5) {
      STAGE(cur ^ 1, (tt + 1) * 64);               // prefetch next tile
      asm volatile("s_waitcnt vmcnt(8)" ::: "memory");   // wait ONLY tile-tt's 8 loads
    } else {
      asm volatile("s_waitcnt vmcnt(0)" ::: "memory");
    }
    __builtin_amdgcn_s_barrier();                  // all waves' tile-tt data visible

#pragma unroll
    for (int kk = 0; kk < 64; kk += 32) {
      bf16x8 af[4], bfv[4];
#pragma unroll
      for (int f = 0; f < 4; ++f) {
        int row = wr * 64 + f * 16 + lr;
        int cb = (kk + lg * 8) * 2;
        af[f] = *reinterpret_cast<const bf16x8*>(
            &lA[cur][row * 64 + ((cb ^ ((row & 7) << 4)) >> 1)]);
      }
#pragma unroll
      for (int f = 0; f < 4; ++f) {
        int row = wc * 64 + f * 16 + lr;
        int cb = (kk + lg * 8) * 2;
        bfv[f] = *reinterpret_cast<const bf16x8*>(
            &lB[cur][row * 64 + ((cb ^ ((row & 7) << 4)) >> 1)]);
      }
#pragma unroll
      for (int fm = 0; fm < 4; ++fm)
#pragma unroll
        for (int fn = 0; fn < 4; ++fn)
          acc[fm][fn] = __builtin_amdgcn_mfma_f32_16x16x32_bf16(af[fm], bfv[fn], acc[fm][fn], 0, 0, 0);
    }
  }
#undef STAGE

  // epilogue: C/D frag mapping col = lane&15, row = (lane>>4)*4 + r  [m89-verified]
#pragma unroll
  for (int fm = 0; fm < 4; ++fm) {
#pragma unroll
    for (int fn = 0; fn < 4; ++fn) {
      int c = n0 + wc * 64 + fn * 16 + lr;
      float bc = bias[c];
#pragma unroll
      for (int r = 0; r < 4; ++r) {
        int m = m0 + wr * 64 + fm * 16 + lg * 4 + r;
        float v = acc[fm][fn][r] + bc;
        if (MODE == 0) {
          int b = m / 49, n = m - b * 49;
          int which = c / 384;
          int rem = c - which * 384;
          int h = rem >> 5, d = rem & 31;
          bf16* dst = which == 0 ? oQ : (which == 1 ? oK : oV);
          dst[((b * 12 + h) * 49 + n) * 32 + d] = (bf16)v;
        } else {
          oP[m * 384 + c] = v;
        }
      }
    }
  }
}

// ---------------- fused window attention: one wave per (b,h), 32x32 MFMA ----------------
// (round-5 green) Swapped QK^T, lane-local softmax, P in registers via
// cvt-pack + permlane32_swap, V staged transposed in LDS. Single bm table.
__global__ __launch_bounds__(256, 4) void k_attn(const bf16* __restrict__ Q,
                                                 const bf16* __restrict__ K,
                                                 const bf16* __restrict__ V,
                                                 const float* __restrict__ bmT,
                                                 bf16* __restrict__ H) {
  __shared__ __align__(16) bf16 Vl[4][32 * 72];
  const int t = threadIdx.x, l = t & 63, wv = t >> 6;
  const int p = blockIdx.x * 4 + wv;   // b*12 + h
  const int b = p / 12, h = p - b * 12;
  const int w = b & 63;
  const size_t base = (size_t)p * (49 * 32);
  const int c = l & 31, b5 = l >> 5;
  bf16* vl = Vl[wv];

  // zero pad keys 48..63 (key 48 re-written by staging below)
  {
    bf16x4 z = {};
    for (int i = l; i < 128; i += 64) {
      int d = i >> 2, kq = 48 + (i & 3) * 4;
      *reinterpret_cast<bf16x4*>(&vl[d * 72 + kq]) = z;
    }
  }
  // stage V transposed: vl[d*72 + key] = V[key*32 + d]
  for (int i = l; i < 392; i += 64) {
    int key = i >> 3, dc = (i & 7) * 4;
    bf16x4 vv = *reinterpret_cast<const bf16x4*>(&V[base + key * 32 + dc]);
#pragma unroll
    for (int j = 0; j < 4; ++j) vl[(dc + j) * 72 + key] = vv[j];
  }

  // K/Q fragments: lane holds X[row = f*32 + c][d = kd*16 + b5*8 + j], rows clamped
  bf16x8 kf[2][2], qf[2][2];
#pragma unroll
  for (int f = 0; f < 2; ++f) {
    int row = f * 32 + c; if (row > 48) row = 48;
#pragma unroll
    for (int kd = 0; kd < 2; ++kd) {
      kf[f][kd] = *reinterpret_cast<const bf16x8*>(&K[base + row * 32 + kd * 16 + b5 * 8]);
      qf[f][kd] = *reinterpret_cast<const bf16x8*>(&Q[base + row * 32 + kd * 16 + b5 * 8]);
    }
  }

  const float scale = 0.17677669529663689f;   // 32^-0.5
  const float* bm = bmT + ((size_t)h * 64 + w) * 2401;

#pragma unroll
  for (int fn = 0; fn < 2; ++fn) {
    // swapped QK^T: S[key][q], C layout col=lane&31=q, row=(r&3)+8*(r>>2)+4*b5=key
    f32x16 s0 = {}, s1 = {};
    s0 = MFMA32(kf[0][0], qf[fn][0], s0);
    s0 = MFMA32(kf[0][1], qf[fn][1], s0);
    s1 = MFMA32(kf[1][0], qf[fn][0], s1);
    s1 = MFMA32(kf[1][1], qf[fn][1], s1);

    int q = fn * 32 + c;
    int qc = q > 48 ? 48 : q;

    float vals[32];
    float vmax = -1e30f;
#pragma unroll
    for (int fm = 0; fm < 2; ++fm) {
#pragma unroll
      for (int r = 0; r < 16; ++r) {
        int key = fm * 32 + (r & 3) + 8 * (r >> 2) + 4 * b5;
        float sv = fm ? s1[r] : s0[r];
        float v;
        if (key < 49) {
          v = fmaf(sv, scale, bm[key * 49 + qc]);
        } else {
          v = -1e30f;
        }
        vals[fm * 16 + r] = v;
        vmax = fmaxf(vmax, v);
      }
    }
    vmax = fmaxf(vmax, __shfl_xor(vmax, 32));
    float sum = 0.f;
#pragma unroll
    for (int i = 0; i < 32; ++i) {
      float e = __expf(vals[i] - vmax);
      vals[i] = e;
      sum += e;
    }
    sum += __shfl_xor(sum, 32);
    float inv = 1.f / sum;

    // PV: build P A-frags in-register (cvt pack + permlane32_swap), MFMA with LDS V
    f32x16 o = {};
#pragma unroll
    for (int kk = 0; kk < 4; ++kk) {
      int ib = (kk >> 1) * 16 + 8 * (kk & 1);
      union { bf16 hh[2]; u32 u; } cv;
      u32 A0, A1, B0, B1;
      cv.hh[0] = (bf16)(vals[ib + 0] * inv); cv.hh[1] = (bf16)(vals[ib + 1] * inv); A0 = cv.u;
      cv.hh[0] = (bf16)(vals[ib + 2] * inv); cv.hh[1] = (bf16)(vals[ib + 3] * inv); A1 = cv.u;
      cv.hh[0] = (bf16)(vals[ib + 4] * inv); cv.hh[1] = (bf16)(vals[ib + 5] * inv); B0 = cv.u;
      cv.hh[0] = (bf16)(vals[ib + 6] * inv); cv.hh[1] = (bf16)(vals[ib + 7] * inv); B1 = cv.u;
      i32x2 sw0 = __builtin_amdgcn_permlane32_swap((int)A0, (int)B0, false, false);
      i32x2 sw1 = __builtin_amdgcn_permlane32_swap((int)A1, (int)B1, false, false);
      union { u32 d[4]; bf16x8 v8; } pa;
      pa.d[0] = (u32)sw0[0]; pa.d[1] = (u32)sw1[0];
      pa.d[2] = (u32)sw0[1]; pa.d[3] = (u32)sw1[1];
      bf16x8 vf = *reinterpret_cast<const bf16x8*>(&vl[c * 72 + kk * 16 + b5 * 8]);
      o = MFMA32(pa.v8, vf, o);
    }

    // store O: row q = fn*32 + (r&3)+8*(r>>2)+4*b5, col d = c
#pragma unroll
    for (int r = 0; r < 16; ++r) {
      int qrow = fn * 32 + (r & 3) + 8 * (r >> 2) + 4 * b5;
      if (qrow < 49)
        H[((size_t)b * 49 + qrow) * 384 + h * 32 + c] = (bf16)o[r];
    }
  }
}

extern "C" void kernel_launch(void* const* d_in, const int* in_sizes, int n_in,
                              void* d_out, int out_size, void* d_ws, size_t ws_size,
                              hipStream_t stream) {
  const float* x     = (const float*)d_in[0];
  const float* mask  = (const float*)d_in[1];
  const float* qkvw  = (const float*)d_in[2];
  const float* qkvb  = (const float*)d_in[3];
  const float* btab  = (const float*)d_in[4];
  const float* projw = (const float*)d_in[5];
  const float* projb = (const float*)d_in[6];
  const int*   rel   = (const int*)d_in[7];
  float* out = (float*)d_out;

  const size_t NB  = 154140672;   // one [200704][384] bf16 buffer (bytes)
  char* ws = (char*)d_ws;
  // ws layout: xb/h [0,NB) | v [NB,2NB) | wqkv (+884736) | wproj (+294912) | bmT (7.4MB)
  bf16*  xb    = (bf16*)ws;
  bf16*  vb    = (bf16*)(ws + NB);
  bf16*  wqkv  = (bf16*)(ws + 2 * NB);
  bf16*  wproj = (bf16*)(ws + 2 * NB + 884736);
  float* bmT   = (float*)(ws + 2 * NB + 884736 + 294912);
  // q,k packed (p,49,32) live in d_out scratch (2*154,140,672 B exactly)
  bf16* qb = (bf16*)d_out;
  bf16* kb = qb + NB / 2;

  k_convert<<<2048, 256, 0, stream>>>((const float4*)x, (bf16x4*)xb, (int)(NB / 8));
  k_convert<<<432, 256, 0, stream>>>((const float4*)qkvw, (bf16x4*)wqkv, 3 * DIMC * DIMC / 4);
  k_convert<<<144, 256, 0, stream>>>((const float4*)projw, (bf16x4*)wproj, DIMC * DIMC / 4);
  k_bm<<<(NHEADS * 64 * NTOK * NTOK + 255) / 256, 256, 0, stream>>>(btab, rel, mask, bmT);

  k_gemm<0><<<dim3(9, MROWS / 128), 256, 0, stream>>>(xb, wqkv, qkvb, qb, kb, vb, nullptr);
  k_attn<<<(NWINB * NHEADS) / 4, 256, 0, stream>>>(qb, kb, vb, bmT, xb);
  k_gemm<1><<<dim3(3, MROWS / 128), 256, 0, stream>>>(xb, wproj, projb, nullptr, nullptr, nullptr, out);
}

// Round 14
// 774.775 us; speedup vs baseline: 1.2464x; 1.0266x over previous
//
#include <hip/hip_runtime.h>

typedef __bf16 bf16;
typedef __bf16 bf16x4 __attribute__((ext_vector_type(4)));
typedef __bf16 bf16x8 __attribute__((ext_vector_type(8)));
typedef float f32x4 __attribute__((ext_vector_type(4)));
typedef float f32x16 __attribute__((ext_vector_type(16)));
typedef int i32x2 __attribute__((ext_vector_type(2)));
typedef unsigned int u32;

#define DIMC 384
#define NHEADS 12
#define NTOK 49
#define NWINB 4096
#define MROWS (NWINB*NTOK)   // 200704

#define MFMA32(A,B,C) __builtin_amdgcn_mfma_f32_32x32x16_bf16(A,B,C,0,0,0)

// async global->LDS, 16B per lane; LDS dest is wave-uniform base + lane*16.
// NOTE: static __shared__ staging only; NEVER reuse this staging region for
// ds_write traffic later in the kernel (r10-r12: et aliased on staging LDS
// -> nondeterministic corruption; r6-r9 separate/non-aliased all green).
#define GLOAD16(gsrc, lbase) \
  __builtin_amdgcn_global_load_lds( \
      (const __attribute__((address_space(1))) u32*)(gsrc), \
      (__attribute__((address_space(3))) u32*)(lbase), 16, 0, 0)

// ---------------- convert f32 -> bf16 (vectorized) ----------------
__global__ __launch_bounds__(256) void k_convert(const float4* __restrict__ in,
                                                 bf16x4* __restrict__ out, int n4) {
  int stride = gridDim.x * blockDim.x;
  for (int i = blockIdx.x * blockDim.x + threadIdx.x; i < n4; i += stride) {
    float4 v = in[i];
    bf16x4 o;
    o[0] = (bf16)v.x; o[1] = (bf16)v.y; o[2] = (bf16)v.z; o[3] = (bf16)v.w;
    out[i] = o;
  }
}

// ---------------- combined transposed bias+mask table (r8/r9-proven) ----------------
// bmT[(h*64+w)][key*49+q] = table[rel[q*49+key]*12+h] + mask[(w*49+q)*49+key]
__global__ __launch_bounds__(256) void k_bm(const float* __restrict__ table,
                                            const int* __restrict__ rel,
                                            const float* __restrict__ mask,
                                            float* __restrict__ outp) {
  int i = blockIdx.x * 256 + threadIdx.x;
  if (i < NHEADS * 64 * NTOK * NTOK) {
    int hw = i / 2401, r2 = i - hw * 2401;
    int h = hw >> 6, w = hw & 63;
    int key = r2 / NTOK, q = r2 - key * NTOK;
    outp[i] = table[rel[q * NTOK + key] * NHEADS + h] + mask[(w * NTOK + q) * NTOK + key];
  }
}

// ---------------- GEMM: C = A(M,K) * Bw(N,K)^T, bf16 in, f32 acc ----------------
// (round-13 green + setprio) BM=128 x BN=128 x BK=64, double-buffered,
// counted vmcnt(8), raw s_barriers, XOR-swizzled static LDS via pre-swizzled
// global source, XCD-chunk remap (contiguous M-panels per XCD).
// MODE 0: QKV (N=1152), scatter q/k/v packed (p,49,32).  MODE 1: proj -> f32+bias.
template <int MODE>
__global__ __launch_bounds__(256) void k_gemm(const bf16* __restrict__ A,
                                              const bf16* __restrict__ Bw,
                                              const float* __restrict__ bias,
                                              bf16* __restrict__ oQ, bf16* __restrict__ oK,
                                              bf16* __restrict__ oV, float* __restrict__ oP) {
  __shared__ __align__(16) bf16 lA[2][128 * 64];
  __shared__ __align__(16) bf16 lB[2][128 * 64];
  const int t = threadIdx.x;
  const int l = t & 63;
  const int wv = t >> 6;
  const int wr = wv >> 1, wc = wv & 1;   // 2x2 waves, 64x64 each

  // ---- bijective XCD-chunk remap (nwg % 8 == 0 for both modes) ----
  const u32 NXB = MODE == 0 ? 9 : 3;                 // N-blocks
  const u32 nwg = NXB * (MROWS / 128);
  u32 lin = blockIdx.y * gridDim.x + blockIdx.x;     // dispatch-linear (x fastest)
  u32 logical = (lin & 7) * (nwg >> 3) + (lin >> 3); // XCD gets contiguous chunk
  const int n0 = (int)(logical % NXB) * 128;
  const int m0 = (int)(logical / NXB) * 128;

  const int lr = l & 15, lg = l >> 4;

  // staging geometry: lane's linear tile byte offset = wv*4096 + i*1024 + l*16
  const int srow = wv * 32 + (l >> 3);           // + i*8 per issue
  const int scolb = (l & 7) * 16;                // byte col within 128B row

  f32x4 acc[4][4] = {};

  // per-lane pre-swizzled source column (elements) for each of the 4 issues
  int scolA[4];
#pragma unroll
  for (int i = 0; i < 4; ++i) {
    int row = srow + i * 8;
    scolA[i] = (scolb ^ ((row & 7) << 4)) >> 1;
  }

#define STAGE(BUF, K0)                                                            \
  {                                                                               \
    _Pragma("unroll") for (int i = 0; i < 4; ++i) {                               \
      int row = srow + i * 8;                                                     \
      GLOAD16(&A[(size_t)(m0 + row) * DIMC + (K0) + scolA[i]],                    \
              &lA[BUF][wv * 2048 + i * 512]);                                     \
      GLOAD16(&Bw[(size_t)(n0 + row) * DIMC + (K0) + scolA[i]],                   \
              &lB[BUF][wv * 2048 + i * 512]);                                     \
    }                                                                             \
  }

  STAGE(0, 0);                      // prologue: tile 0 in flight

#pragma unroll
  for (int tt = 0; tt < 6; ++tt) {  // K = 384 = 6 x 64, fully unrolled
    const int cur = tt & 1;
    if (tt > 0) __builtin_amdgcn_s_barrier();      // compute(tt-1) done -> buf reuse safe
    if (tt < 5) {
      STAGE(cur ^ 1, (tt + 1) * 64);               // prefetch next tile
      asm volatile("s_waitcnt vmcnt(8)" ::: "memory");   // wait ONLY tile-tt's 8 loads
    } else {
      asm volatile("s_waitcnt vmcnt(0)" ::: "memory");
    }
    __builtin_amdgcn_s_barrier();                  // all waves' tile-tt data visible

#pragma unroll
    for (int kk = 0; kk < 64; kk += 32) {
      bf16x8 af[4], bfv[4];
#pragma unroll
      for (int f = 0; f < 4; ++f) {
        int row = wr * 64 + f * 16 + lr;
        int cb = (kk + lg * 8) * 2;
        af[f] = *reinterpret_cast<const bf16x8*>(
            &lA[cur][row * 64 + ((cb ^ ((row & 7) << 4)) >> 1)]);
      }
#pragma unroll
      for (int f = 0; f < 4; ++f) {
        int row = wc * 64 + f * 16 + lr;
        int cb = (kk + lg * 8) * 2;
        bfv[f] = *reinterpret_cast<const bf16x8*>(
            &lB[cur][row * 64 + ((cb ^ ((row & 7) << 4)) >> 1)]);
      }
      __builtin_amdgcn_s_setprio(1);               // T5: favor MFMA-entering wave
#pragma unroll
      for (int fm = 0; fm < 4; ++fm)
#pragma unroll
        for (int fn = 0; fn < 4; ++fn)
          acc[fm][fn] = __builtin_amdgcn_mfma_f32_16x16x32_bf16(af[fm], bfv[fn], acc[fm][fn], 0, 0, 0);
      __builtin_amdgcn_s_setprio(0);
    }
  }
#undef STAGE

  // epilogue: C/D frag mapping col = lane&15, row = (lane>>4)*4 + r  [m89-verified]
#pragma unroll
  for (int fm = 0; fm < 4; ++fm) {
#pragma unroll
    for (int fn = 0; fn < 4; ++fn) {
      int c = n0 + wc * 64 + fn * 16 + lr;
      float bc = bias[c];
#pragma unroll
      for (int r = 0; r < 4; ++r) {
        int m = m0 + wr * 64 + fm * 16 + lg * 4 + r;
        float v = acc[fm][fn][r] + bc;
        if (MODE == 0) {
          int b = m / 49, n = m - b * 49;
          int which = c / 384;
          int rem = c - which * 384;
          int h = rem >> 5, d = rem & 31;
          bf16* dst = which == 0 ? oQ : (which == 1 ? oK : oV);
          dst[((b * 12 + h) * 49 + n) * 32 + d] = (bf16)v;
        } else {
          oP[m * 384 + c] = v;
        }
      }
    }
  }
}

// ---------------- fused window attention: one wave per (b,h), 32x32 MFMA ----------------
// (round-13 green + setprio + no-max softmax) Swapped QK^T, lane-local softmax,
// P in registers via cvt-pack + permlane32_swap, V staged transposed in LDS.
// Max-subtract dropped: |scores| <= ~6 (S*scale sigma 0.15 + mask sigma 1.0), so
// exp() is safely in range in f32 and softmax is shift-invariant.
__global__ __launch_bounds__(256, 4) void k_attn(const bf16* __restrict__ Q,
                                                 const bf16* __restrict__ K,
                                                 const bf16* __restrict__ V,
                                                 const float* __restrict__ bmT,
                                                 bf16* __restrict__ H) {
  __shared__ __align__(16) bf16 Vl[4][32 * 72];
  const int t = threadIdx.x, l = t & 63, wv = t >> 6;
  const int p = blockIdx.x * 4 + wv;   // b*12 + h
  const int b = p / 12, h = p - b * 12;
  const int w = b & 63;
  const size_t base = (size_t)p * (49 * 32);
  const int c = l & 31, b5 = l >> 5;
  bf16* vl = Vl[wv];

  // zero pad keys 48..63 (key 48 re-written by staging below)
  {
    bf16x4 z = {};
    for (int i = l; i < 128; i += 64) {
      int d = i >> 2, kq = 48 + (i & 3) * 4;
      *reinterpret_cast<bf16x4*>(&vl[d * 72 + kq]) = z;
    }
  }
  // stage V transposed: vl[d*72 + key] = V[key*32 + d]
  for (int i = l; i < 392; i += 64) {
    int key = i >> 3, dc = (i & 7) * 4;
    bf16x4 vv = *reinterpret_cast<const bf16x4*>(&V[base + key * 32 + dc]);
#pragma unroll
    for (int j = 0; j < 4; ++j) vl[(dc + j) * 72 + key] = vv[j];
  }

  // K/Q fragments: lane holds X[row = f*32 + c][d = kd*16 + b5*8 + j], rows clamped
  bf16x8 kf[2][2], qf[2][2];
#pragma unroll
  for (int f = 0; f < 2; ++f) {
    int row = f * 32 + c; if (row > 48) row = 48;
#pragma unroll
    for (int kd = 0; kd < 2; ++kd) {
      kf[f][kd] = *reinterpret_cast<const bf16x8*>(&K[base + row * 32 + kd * 16 + b5 * 8]);
      qf[f][kd] = *reinterpret_cast<const bf16x8*>(&Q[base + row * 32 + kd * 16 + b5 * 8]);
    }
  }

  const float scale = 0.17677669529663689f;   // 32^-0.5
  const float* bm = bmT + ((size_t)h * 64 + w) * 2401;

#pragma unroll
  for (int fn = 0; fn < 2; ++fn) {
    // swapped QK^T: S[key][q], C layout col=lane&31=q, row=(r&3)+8*(r>>2)+4*b5=key
    f32x16 s0 = {}, s1 = {};
    __builtin_amdgcn_s_setprio(1);
    s0 = MFMA32(kf[0][0], qf[fn][0], s0);
    s0 = MFMA32(kf[0][1], qf[fn][1], s0);
    s1 = MFMA32(kf[1][0], qf[fn][0], s1);
    s1 = MFMA32(kf[1][1], qf[fn][1], s1);
    __builtin_amdgcn_s_setprio(0);

    int q = fn * 32 + c;
    int qc = q > 48 ? 48 : q;

    // softmax without max-subtract: e = exp(score), row-sum via 1 permlane-pair
    float vals[32];
    float sum = 0.f;
#pragma unroll
    for (int fm = 0; fm < 2; ++fm) {
#pragma unroll
      for (int r = 0; r < 16; ++r) {
        int key = fm * 32 + (r & 3) + 8 * (r >> 2) + 4 * b5;
        float sv = fm ? s1[r] : s0[r];
        float e;
        if (key < 49) {
          e = __expf(fmaf(sv, scale, bm[key * 49 + qc]));
        } else {
          e = 0.f;
        }
        vals[fm * 16 + r] = e;
        sum += e;
      }
    }
    sum += __shfl_xor(sum, 32);
    float inv = 1.f / sum;

    // PV: build P A-frags in-register (cvt pack + permlane32_swap), MFMA with LDS V
    f32x16 o = {};
#pragma unroll
    for (int kk = 0; kk < 4; ++kk) {
      int ib = (kk >> 1) * 16 + 8 * (kk & 1);
      union { bf16 hh[2]; u32 u; } cv;
      u32 A0, A1, B0, B1;
      cv.hh[0] = (bf16)(vals[ib + 0] * inv); cv.hh[1] = (bf16)(vals[ib + 1] * inv); A0 = cv.u;
      cv.hh[0] = (bf16)(vals[ib + 2] * inv); cv.hh[1] = (bf16)(vals[ib + 3] * inv); A1 = cv.u;
      cv.hh[0] = (bf16)(vals[ib + 4] * inv); cv.hh[1] = (bf16)(vals[ib + 5] * inv); B0 = cv.u;
      cv.hh[0] = (bf16)(vals[ib + 6] * inv); cv.hh[1] = (bf16)(vals[ib + 7] * inv); B1 = cv.u;
      i32x2 sw0 = __builtin_amdgcn_permlane32_swap((int)A0, (int)B0, false, false);
      i32x2 sw1 = __builtin_amdgcn_permlane32_swap((int)A1, (int)B1, false, false);
      union { u32 d[4]; bf16x8 v8; } pa;
      pa.d[0] = (u32)sw0[0]; pa.d[1] = (u32)sw1[0];
      pa.d[2] = (u32)sw0[1]; pa.d[3] = (u32)sw1[1];
      bf16x8 vf = *reinterpret_cast<const bf16x8*>(&vl[c * 72 + kk * 16 + b5 * 8]);
      __builtin_amdgcn_s_setprio(1);
      o = MFMA32(pa.v8, vf, o);
      __builtin_amdgcn_s_setprio(0);
    }

    // store O: row q = fn*32 + (r&3)+8*(r>>2)+4*b5, col d = c
#pragma unroll
    for (int r = 0; r < 16; ++r) {
      int qrow = fn * 32 + (r & 3) + 8 * (r >> 2) + 4 * b5;
      if (qrow < 49)
        H[((size_t)b * 49 + qrow) * 384 + h * 32 + c] = (bf16)o[r];
    }
  }
}

extern "C" void kernel_launch(void* const* d_in, const int* in_sizes, int n_in,
                              void* d_out, int out_size, void* d_ws, size_t ws_size,
                              hipStream_t stream) {
  const float* x     = (const float*)d_in[0];
  const float* mask  = (const float*)d_in[1];
  const float* qkvw  = (const float*)d_in[2];
  const float* qkvb  = (const float*)d_in[3];
  const float* btab  = (const float*)d_in[4];
  const float* projw = (const float*)d_in[5];
  const float* projb = (const float*)d_in[6];
  const int*   rel   = (const int*)d_in[7];
  float* out = (float*)d_out;

  const size_t NB  = 154140672;   // one [200704][384] bf16 buffer (bytes)
  char* ws = (char*)d_ws;
  // ws layout: xb/h [0,NB) | v [NB,2NB) | wqkv (+884736) | wproj (+294912) | bmT (7.4MB)
  bf16*  xb    = (bf16*)ws;
  bf16*  vb    = (bf16*)(ws + NB);
  bf16*  wqkv  = (bf16*)(ws + 2 * NB);
  bf16*  wproj = (bf16*)(ws + 2 * NB + 884736);
  float* bmT   = (float*)(ws + 2 * NB + 884736 + 294912);
  // q,k packed (p,49,32) live in d_out scratch (2*154,140,672 B exactly)
  bf16* qb = (bf16*)d_out;
  bf16* kb = qb + NB / 2;

  k_convert<<<2048, 256, 0, stream>>>((const float4*)x, (bf16x4*)xb, (int)(NB / 8));
  k_convert<<<432, 256, 0, stream>>>((const float4*)qkvw, (bf16x4*)wqkv, 3 * DIMC * DIMC / 4);
  k_convert<<<144, 256, 0, stream>>>((const float4*)projw, (bf16x4*)wproj, DIMC * DIMC / 4);
  k_bm<<<(NHEADS * 64 * NTOK * NTOK + 255) / 256, 256, 0, stream>>>(btab, rel, mask, bmT);

  k_gemm<0><<<dim3(9, MROWS / 128), 256, 0, stream>>>(xb, wqkv, qkvb, qb, kb, vb, nullptr);
  k_attn<<<(NWINB * NHEADS) / 4, 256, 0, stream>>>(qb, kb, vb, bmT, xb);
  k_gemm<1><<<dim3(3, MROWS / 128), 256, 0, stream>>>(xb, wproj, projb, nullptr, nullptr, nullptr, out);
}

// Round 16
// 763.104 us; speedup vs baseline: 1.2655x; 1.0153x over previous
//
#include <hip/hip_runtime.h>

typedef __bf16 bf16;
typedef __bf16 bf16x4 __attribute__((ext_vector_type(4)));
typedef __bf16 bf16x8 __attribute__((ext_vector_type(8)));
typedef float f32x4 __attribute__((ext_vector_type(4)));
typedef float f32x16 __attribute__((ext_vector_type(16)));
typedef int i32x2 __attribute__((ext_vector_type(2)));
typedef unsigned int u32;

#define DIMC 384
#define NHEADS 12
#define NTOK 49
#define NWINB 4096
#define MROWS (NWINB*NTOK)   // 200704

#define MFMA32(A,B,C) __builtin_amdgcn_mfma_f32_32x32x16_bf16(A,B,C,0,0,0)

// async global->LDS, 16B per lane; LDS dest is wave-uniform base + lane*16.
// RULES (learned r10-r12, r15): (1) static __shared__ staging only; (2) never
// reuse the staging region for ds_write traffic later in the kernel; (3) manual
// counted vmcnt is only valid when EVERY in-loop VMEM op is an explicit
// intrinsic — no compiler-materialized global loads in the counted window.
#define GLOAD16(gsrc, lbase) \
  __builtin_amdgcn_global_load_lds( \
      (const __attribute__((address_space(1))) u32*)(gsrc), \
      (__attribute__((address_space(3))) u32*)(lbase), 16, 0, 0)

// ---------------- convert f32 -> bf16 (vectorized) ----------------
__global__ __launch_bounds__(256) void k_convert(const float4* __restrict__ in,
                                                 bf16x4* __restrict__ out, int n4) {
  int stride = gridDim.x * blockDim.x;
  for (int i = blockIdx.x * blockDim.x + threadIdx.x; i < n4; i += stride) {
    float4 v = in[i];
    bf16x4 o;
    o[0] = (bf16)v.x; o[1] = (bf16)v.y; o[2] = (bf16)v.z; o[3] = (bf16)v.w;
    out[i] = o;
  }
}

// ---------------- combined transposed bias+mask table (r8/r9-proven) ----------------
// bmT[(h*64+w)][key*49+q] = table[rel[q*49+key]*12+h] + mask[(w*49+q)*49+key]
__global__ __launch_bounds__(256) void k_bm(const float* __restrict__ table,
                                            const int* __restrict__ rel,
                                            const float* __restrict__ mask,
                                            float* __restrict__ outp) {
  int i = blockIdx.x * 256 + threadIdx.x;
  if (i < NHEADS * 64 * NTOK * NTOK) {
    int hw = i / 2401, r2 = i - hw * 2401;
    int h = hw >> 6, w = hw & 63;
    int key = r2 / NTOK, q = r2 - key * NTOK;
    outp[i] = table[rel[q * NTOK + key] * NHEADS + h] + mask[(w * NTOK + q) * NTOK + key];
  }
}

// ---------------- GEMM: C = A(M,K) * Bw(N,K)^T, bf16 in, f32 acc ----------------
// (r13 green, byte-identical — no setprio: A/B r13 vs r14 showed setprio costs
// ~9us on this lockstep 2-phase GEMM) BM=128 x BN=128 x BK=64, double-buffered,
// counted vmcnt(8), raw s_barriers, XOR-swizzled static LDS via pre-swizzled
// global source, XCD-chunk remap (contiguous M-panels per XCD).
// MODE 0: QKV (N=1152), scatter q/k/v packed (p,49,32).  MODE 1: proj -> f32+bias.
template <int MODE>
__global__ __launch_bounds__(256) void k_gemm(const bf16* __restrict__ A,
                                              const bf16* __restrict__ Bw,
                                              const float* __restrict__ bias,
                                              bf16* __restrict__ oQ, bf16* __restrict__ oK,
                                              bf16* __restrict__ oV, float* __restrict__ oP) {
  __shared__ __align__(16) bf16 lA[2][128 * 64];
  __shared__ __align__(16) bf16 lB[2][128 * 64];
  const int t = threadIdx.x;
  const int l = t & 63;
  const int wv = t >> 6;
  const int wr = wv >> 1, wc = wv & 1;   // 2x2 waves, 64x64 each

  // ---- bijective XCD-chunk remap (nwg % 8 == 0 for both modes) ----
  const u32 NXB = MODE == 0 ? 9 : 3;                 // N-blocks
  const u32 nwg = NXB * (MROWS / 128);
  u32 lin = blockIdx.y * gridDim.x + blockIdx.x;     // dispatch-linear (x fastest)
  u32 logical = (lin & 7) * (nwg >> 3) + (lin >> 3); // XCD gets contiguous chunk
  const int n0 = (int)(logical % NXB) * 128;
  const int m0 = (int)(logical / NXB) * 128;

  const int lr = l & 15, lg = l >> 4;

  // staging geometry: lane's linear tile byte offset = wv*4096 + i*1024 + l*16
  const int srow = wv * 32 + (l >> 3);           // + i*8 per issue
  const int scolb = (l & 7) * 16;                // byte col within 128B row

  f32x4 acc[4][4] = {};

  // per-lane pre-swizzled source column (elements) for each of the 4 issues
  int scolA[4];
#pragma unroll
  for (int i = 0; i < 4; ++i) {
    int row = srow + i * 8;
    scolA[i] = (scolb ^ ((row & 7) << 4)) >> 1;
  }

#define STAGE(BUF, K0)                                                            \
  {                                                                               \
    _Pragma("unroll") for (int i = 0; i < 4; ++i) {                               \
      int row = srow + i * 8;                                                     \
      GLOAD16(&A[(size_t)(m0 + row) * DIMC + (K0) + scolA[i]],                    \
              &lA[BUF][wv * 2048 + i * 512]);                                     \
      GLOAD16(&Bw[(size_t)(n0 + row) * DIMC + (K0) + scolA[i]],                   \
              &lB[BUF][wv * 2048 + i * 512]);                                     \
    }                                                                             \
  }

  STAGE(0, 0);                      // prologue: tile 0 in flight

#pragma unroll
  for (int tt = 0; tt < 6; ++tt) {  // K = 384 = 6 x 64, fully unrolled
    const int cur = tt & 1;
    if (tt > 0) __builtin_amdgcn_s_barrier();      // compute(tt-1) done -> buf reuse safe
    if (tt < 5) {
      STAGE(cur ^ 1, (tt + 1) * 64);               // prefetch next tile
      asm volatile("s_waitcnt vmcnt(8)" ::: "memory");   // wait ONLY tile-tt's 8 loads
    } else {
      asm volatile("s_waitcnt vmcnt(0)" ::: "memory");
    }
    __builtin_amdgcn_s_barrier();                  // all waves' tile-tt data visible

#pragma unroll
    for (int kk = 0; kk < 64; kk += 32) {
      bf16x8 af[4], bfv[4];
#pragma unroll
      for (int f = 0; f < 4; ++f) {
        int row = wr * 64 + f * 16 + lr;
        int cb = (kk + lg * 8) * 2;
        af[f] = *reinterpret_cast<const bf16x8*>(
            &lA[cur][row * 64 + ((cb ^ ((row & 7) << 4)) >> 1)]);
      }
#pragma unroll
      for (int f = 0; f < 4; ++f) {
        int row = wc * 64 + f * 16 + lr;
        int cb = (kk + lg * 8) * 2;
        bfv[f] = *reinterpret_cast<const bf16x8*>(
            &lB[cur][row * 64 + ((cb ^ ((row & 7) << 4)) >> 1)]);
      }
#pragma unroll
      for (int fm = 0; fm < 4; ++fm)
#pragma unroll
        for (int fn = 0; fn < 4; ++fn)
          acc[fm][fn] = __builtin_amdgcn_mfma_f32_16x16x32_bf16(af[fm], bfv[fn], acc[fm][fn], 0, 0, 0);
    }
  }
#undef STAGE

  // epilogue: C/D frag mapping col = lane&15, row = (lane>>4)*4 + r  [m89-verified]
#pragma unroll
  for (int fm = 0; fm < 4; ++fm) {
#pragma unroll
    for (int fn = 0; fn < 4; ++fn) {
      int c = n0 + wc * 64 + fn * 16 + lr;
      float bc = bias[c];
#pragma unroll
      for (int r = 0; r < 4; ++r) {
        int m = m0 + wr * 64 + fm * 16 + lg * 4 + r;
        float v = acc[fm][fn][r] + bc;
        if (MODE == 0) {
          int b = m / 49, n = m - b * 49;
          int which = c / 384;
          int rem = c - which * 384;
          int h = rem >> 5, d = rem & 31;
          bf16* dst = which == 0 ? oQ : (which == 1 ? oK : oV);
          dst[((b * 12 + h) * 49 + n) * 32 + d] = (bf16)v;
        } else {
          oP[m * 384 + c] = v;
        }
      }
    }
  }
}

// ---------------- fused window attention: one wave per (b,h), 32x32 MFMA ----------------
// (r14 green, unchanged) Swapped QK^T, lane-local no-max softmax (|score| <= ~6,
// f32-safe; softmax shift-invariant), P in registers via cvt-pack +
// permlane32_swap, V staged transposed in LDS, setprio around MFMA (helps here:
// independent waves at different phases — r14 A/B).
__global__ __launch_bounds__(256, 4) void k_attn(const bf16* __restrict__ Q,
                                                 const bf16* __restrict__ K,
                                                 const bf16* __restrict__ V,
                                                 const float* __restrict__ bmT,
                                                 bf16* __restrict__ H) {
  __shared__ __align__(16) bf16 Vl[4][32 * 72];
  const int t = threadIdx.x, l = t & 63, wv = t >> 6;
  const int p = blockIdx.x * 4 + wv;   // b*12 + h
  const int b = p / 12, h = p - b * 12;
  const int w = b & 63;
  const size_t base = (size_t)p * (49 * 32);
  const int c = l & 31, b5 = l >> 5;
  bf16* vl = Vl[wv];

  // zero pad keys 48..63 (key 48 re-written by staging below)
  {
    bf16x4 z = {};
    for (int i = l; i < 128; i += 64) {
      int d = i >> 2, kq = 48 + (i & 3) * 4;
      *reinterpret_cast<bf16x4*>(&vl[d * 72 + kq]) = z;
    }
  }
  // stage V transposed: vl[d*72 + key] = V[key*32 + d]
  for (int i = l; i < 392; i += 64) {
    int key = i >> 3, dc = (i & 7) * 4;
    bf16x4 vv = *reinterpret_cast<const bf16x4*>(&V[base + key * 32 + dc]);
#pragma unroll
    for (int j = 0; j < 4; ++j) vl[(dc + j) * 72 + key] = vv[j];
  }

  // K/Q fragments: lane holds X[row = f*32 + c][d = kd*16 + b5*8 + j], rows clamped
  bf16x8 kf[2][2], qf[2][2];
#pragma unroll
  for (int f = 0; f < 2; ++f) {
    int row = f * 32 + c; if (row > 48) row = 48;
#pragma unroll
    for (int kd = 0; kd < 2; ++kd) {
      kf[f][kd] = *reinterpret_cast<const bf16x8*>(&K[base + row * 32 + kd * 16 + b5 * 8]);
      qf[f][kd] = *reinterpret_cast<const bf16x8*>(&Q[base + row * 32 + kd * 16 + b5 * 8]);
    }
  }

  const float scale = 0.17677669529663689f;   // 32^-0.5
  const float* bm = bmT + ((size_t)h * 64 + w) * 2401;

#pragma unroll
  for (int fn = 0; fn < 2; ++fn) {
    // swapped QK^T: S[key][q], C layout col=lane&31=q, row=(r&3)+8*(r>>2)+4*b5=key
    f32x16 s0 = {}, s1 = {};
    __builtin_amdgcn_s_setprio(1);
    s0 = MFMA32(kf[0][0], qf[fn][0], s0);
    s0 = MFMA32(kf[0][1], qf[fn][1], s0);
    s1 = MFMA32(kf[1][0], qf[fn][0], s1);
    s1 = MFMA32(kf[1][1], qf[fn][1], s1);
    __builtin_amdgcn_s_setprio(0);

    int q = fn * 32 + c;
    int qc = q > 48 ? 48 : q;

    // softmax without max-subtract: e = exp(score); |score| <= ~6 in f32-safe range
    float vals[32];
    float sum = 0.f;
#pragma unroll
    for (int fm = 0; fm < 2; ++fm) {
#pragma unroll
      for (int r = 0; r < 16; ++r) {
        int key = fm * 32 + (r & 3) + 8 * (r >> 2) + 4 * b5;
        float sv = fm ? s1[r] : s0[r];
        float e;
        if (key < 49) {
          e = __expf(fmaf(sv, scale, bm[key * 49 + qc]));
        } else {
          e = 0.f;
        }
        vals[fm * 16 + r] = e;
        sum += e;
      }
    }
    sum += __shfl_xor(sum, 32);
    float inv = 1.f / sum;

    // PV: build P A-frags in-register (cvt pack + permlane32_swap), MFMA with LDS V
    f32x16 o = {};
#pragma unroll
    for (int kk = 0; kk < 4; ++kk) {
      int ib = (kk >> 1) * 16 + 8 * (kk & 1);
      union { bf16 hh[2]; u32 u; } cv;
      u32 A0, A1, B0, B1;
      cv.hh[0] = (bf16)(vals[ib + 0] * inv); cv.hh[1] = (bf16)(vals[ib + 1] * inv); A0 = cv.u;
      cv.hh[0] = (bf16)(vals[ib + 2] * inv); cv.hh[1] = (bf16)(vals[ib + 3] * inv); A1 = cv.u;
      cv.hh[0] = (bf16)(vals[ib + 4] * inv); cv.hh[1] = (bf16)(vals[ib + 5] * inv); B0 = cv.u;
      cv.hh[0] = (bf16)(vals[ib + 6] * inv); cv.hh[1] = (bf16)(vals[ib + 7] * inv); B1 = cv.u;
      i32x2 sw0 = __builtin_amdgcn_permlane32_swap((int)A0, (int)B0, false, false);
      i32x2 sw1 = __builtin_amdgcn_permlane32_swap((int)A1, (int)B1, false, false);
      union { u32 d[4]; bf16x8 v8; } pa;
      pa.d[0] = (u32)sw0[0]; pa.d[1] = (u32)sw1[0];
      pa.d[2] = (u32)sw0[1]; pa.d[3] = (u32)sw1[1];
      bf16x8 vf = *reinterpret_cast<const bf16x8*>(&vl[c * 72 + kk * 16 + b5 * 8]);
      __builtin_amdgcn_s_setprio(1);
      o = MFMA32(pa.v8, vf, o);
      __builtin_amdgcn_s_setprio(0);
    }

    // store O: row q = fn*32 + (r&3)+8*(r>>2)+4*b5, col d = c
#pragma unroll
    for (int r = 0; r < 16; ++r) {
      int qrow = fn * 32 + (r & 3) + 8 * (r >> 2) + 4 * b5;
      if (qrow < 49)
        H[((size_t)b * 49 + qrow) * 384 + h * 32 + c] = (bf16)o[r];
    }
  }
}

extern "C" void kernel_launch(void* const* d_in, const int* in_sizes, int n_in,
                              void* d_out, int out_size, void* d_ws, size_t ws_size,
                              hipStream_t stream) {
  const float* x     = (const float*)d_in[0];
  const float* mask  = (const float*)d_in[1];
  const float* qkvw  = (const float*)d_in[2];
  const float* qkvb  = (const float*)d_in[3];
  const float* btab  = (const float*)d_in[4];
  const float* projw = (const float*)d_in[5];
  const float* projb = (const float*)d_in[6];
  const int*   rel   = (const int*)d_in[7];
  float* out = (float*)d_out;

  const size_t NB  = 154140672;   // one [200704][384] bf16 buffer (bytes)
  char* ws = (char*)d_ws;
  // ws layout: xb/h [0,NB) | v [NB,2NB) | wqkv (+884736) | wproj (+294912) | bmT (7.4MB)
  bf16*  xb    = (bf16*)ws;
  bf16*  vb    = (bf16*)(ws + NB);
  bf16*  wqkv  = (bf16*)(ws + 2 * NB);
  bf16*  wproj = (bf16*)(ws + 2 * NB + 884736);
  float* bmT   = (float*)(ws + 2 * NB + 884736 + 294912);
  // q,k packed (p,49,32) live in d_out scratch (2*154,140,672 B exactly)
  bf16* qb = (bf16*)d_out;
  bf16* kb = qb + NB / 2;

  k_convert<<<2048, 256, 0, stream>>>((const float4*)x, (bf16x4*)xb, (int)(NB / 8));
  k_convert<<<432, 256, 0, stream>>>((const float4*)qkvw, (bf16x4*)wqkv, 3 * DIMC * DIMC / 4);
  k_convert<<<144, 256, 0, stream>>>((const float4*)projw, (bf16x4*)wproj, DIMC * DIMC / 4);
  k_bm<<<(NHEADS * 64 * NTOK * NTOK + 255) / 256, 256, 0, stream>>>(btab, rel, mask, bmT);

  k_gemm<0><<<dim3(9, MROWS / 128), 256, 0, stream>>>(xb, wqkv, qkvb, qb, kb, vb, nullptr);
  k_attn<<<(NWINB * NHEADS) / 4, 256, 0, stream>>>(qb, kb, vb, bmT, xb);
  k_gemm<1><<<dim3(3, MROWS / 128), 256, 0, stream>>>(xb, wproj, projb, nullptr, nullptr, nullptr, out);
}